// Round 6
// 18302.054 us; speedup vs baseline: 1.0087x; 1.0087x over previous
//
#include <hip/hip_runtime.h>
#include <stdint.h>

#define T_STEPS 8192
#define HID     1024
#define IN_F    2048
#define N3H     3072   // 3*HID
#define NREP    8      // exchange-buffer replicas (spread coherence-point lines)

// ---------------------------------------------------------------------------
// Exchange format: one u32 per h element; low 2 mantissa bits = step tag
// (step & 3). Double-buffered (buffer s&1 holds h of step s); stale content
// is from step s-2 (tag differs mod 4). Full-vector detection bounds wg skew
// below 2 steps, so neither past (s-4) nor future (s+4) mod-4 aliases can be
// observed: a wg at head k has itself observed h^{k-2} in buffer k&1
// (monotone coherence-point reads exclude older), and no producer can write
// h^{k+2} into buffer k&1 until every wg stored h^{k+1}, i.e. passed head k.
// Replicated NREP x: producers store to every replica, consumer wg g polls
// replica g&(NREP-1) only. h_0 = 0.0f with tag 0 == 0x0 -> zero-init.
//
// SAFETY DISCIPLINE (post r2-r5 races): NO split issue/wait asm. The probe
// is ONE fused asm (load + s_waitcnt vmcnt(0)) so its output is complete at
// the asm boundary -- consumers carry a true data dependence, nothing can
// be hoisted past an unfinished load, and no in-flight load ever has a
// compiler-dead destination. Poll exit is wave-uniform (__all) so every
// probe executes with FULL exec and fully redefines its "=v" destination
// (partially-masked re-issues were the r2/r3 corruption). Re-reading an
// already-good word is monotone-safe (see above).
// ---------------------------------------------------------------------------
__global__ void init_pairs(unsigned int* pairs) {
    int i = blockIdx.x * blockDim.x + threadIdx.x;
    if (i < 2 * NREP * HID) pairs[i] = 0u;
}

// fused scoped 16B probe: bypass L1/L2 (sc0 sc1) so cross-XCD stores are
// visible; per-32-bit-word atomicity from natural alignment (tearing across
// words fine -- each word carries its own tag). vmcnt(0) INSIDE the asm.
__device__ __forceinline__ uint4 load_x4_scoped(const unsigned int* p) {
    uint4 r;
    asm volatile("global_load_dwordx4 %0, %1, off sc0 sc1\n\t"
                 "s_waitcnt vmcnt(0)"
                 : "=v"(r) : "v"(p) : "memory");
    return r;
}
__device__ __forceinline__ void store_scoped(unsigned int* p, unsigned int v) {
    asm volatile("global_store_dword %0, %1, off sc0 sc1"
                 :: "v"(p), "v"(v) : "memory");
}
__device__ __forceinline__ int tag_ok(const uint4& v, unsigned int w) {
    return (((v.x & 3u) == w) & ((v.y & 3u) == w) &
            ((v.z & 3u) == w) & ((v.w & 3u) == w));
}

// ---------------------------------------------------------------------------
// Phase 1: gi[t, j'] = x[t] . w_ih[j'] + b_ih[j']  (unchanged, ~1.4 ms)
// ---------------------------------------------------------------------------
#define GBM 64
#define GBN 64
#define GBK 32

__global__ __launch_bounds__(256) void gi_gemm(
    const float* __restrict__ feat,   // [8192][2048]
    const float* __restrict__ rew,    // [8192]
    const float* __restrict__ w_ih,   // [3072][2049]
    const float* __restrict__ b_ih,   // [3072]
    float* __restrict__ gi)           // [8192][3072]
{
    __shared__ float As[GBK][GBM + 4];
    __shared__ float Bs[GBK][GBN + 4];

    const int tid = threadIdx.x;
    const int n0 = blockIdx.x * GBN;
    const int t0 = blockIdx.y * GBM;
    const int tx = tid & 15, ty = tid >> 4;
    const int lr = tid >> 3;
    const int lc = (tid & 7) * 4;

    float acc[4][4] = {{0.f}};

    for (int k0 = 0; k0 < IN_F; k0 += GBK) {
#pragma unroll
        for (int hh = 0; hh < 2; hh++) {
            const int r = lr + 32 * hh;
            const float4 a = *(const float4*)(feat + (size_t)(t0 + r) * IN_F + k0 + lc);
            As[lc + 0][r] = a.x; As[lc + 1][r] = a.y;
            As[lc + 2][r] = a.z; As[lc + 3][r] = a.w;
            const float* brow = w_ih + (size_t)(n0 + r) * (IN_F + 1) + k0 + lc;
            Bs[lc + 0][r] = brow[0]; Bs[lc + 1][r] = brow[1];
            Bs[lc + 2][r] = brow[2]; Bs[lc + 3][r] = brow[3];
        }
        __syncthreads();
#pragma unroll
        for (int kk = 0; kk < GBK; kk++) {
            const float4 a = *(const float4*)&As[kk][ty * 4];
            const float4 b = *(const float4*)&Bs[kk][tx * 4];
            acc[0][0] += a.x * b.x; acc[0][1] += a.x * b.y; acc[0][2] += a.x * b.z; acc[0][3] += a.x * b.w;
            acc[1][0] += a.y * b.x; acc[1][1] += a.y * b.y; acc[1][2] += a.y * b.z; acc[1][3] += a.y * b.w;
            acc[2][0] += a.z * b.x; acc[2][1] += a.z * b.y; acc[2][2] += a.z * b.z; acc[2][3] += a.z * b.w;
            acc[3][0] += a.w * b.x; acc[3][1] += a.w * b.y; acc[3][2] += a.w * b.z; acc[3][3] += a.w * b.w;
        }
        __syncthreads();
    }

    const int m = t0 + ty * 4;
    const int n = n0 + tx * 4;
    float wlast[4], bi[4];
#pragma unroll
    for (int c = 0; c < 4; c++) {
        wlast[c] = w_ih[(size_t)(n + c) * (IN_F + 1) + IN_F];
        bi[c]    = b_ih[n + c];
    }
#pragma unroll
    for (int r = 0; r < 4; r++) {
        const float rwv = rew[m + r];
        float4 v;
        v.x = acc[r][0] + rwv * wlast[0] + bi[0];
        v.y = acc[r][1] + rwv * wlast[1] + bi[1];
        v.z = acc[r][2] + rwv * wlast[2] + bi[2];
        v.w = acc[r][3] + rwv * wlast[3] + bi[3];
        *(float4*)(gi + (size_t)(m + r) * N3H + n) = v;
    }
}

// ---------------------------------------------------------------------------
// Phase 2: persistent GRU scan. 256 wgs x 256 threads; wg g owns j in
// [4g,4g+4), one j per wave. Weights in static LDS (48 KB). h_lds is
// double-buffered so ONE __syncthreads per step suffices: step-i readers of
// h_lds[i&1] all arrive at barrier_{i+1} before any wave reaches head i+2
// (the next writer of h_lds[i&1]); __syncthreads is a full compiler fence,
// so no LDS access moves across it. The global protocol independently
// guarantees no wave passes head i+1 until every wave stored h^{i+1}, i.e.
// finished its step-i compute.
// ---------------------------------------------------------------------------
__global__ __launch_bounds__(256, 2) void gru_scan(
    const float* __restrict__ gi,     // [8192][3072]
    const float* __restrict__ w_hh,   // [3072][1024]
    const float* __restrict__ b_hh,   // [3072]
    unsigned int* pairs,              // [2][NREP][1024] tagged fp32
    float* __restrict__ out)          // [1024]
{
    __shared__ float4 w_lds[3][4][HID / 4];  // 48 KB
    __shared__ float4 h_lds[2][HID / 4];     // 8 KB, double-buffered

    const int tid  = threadIdx.x;
    const int g    = blockIdx.x;      // 0..255
    const int j0   = g * 4;
    const int wave = tid >> 6;
    const int lane = tid & 63;
    const int myj  = j0 + wave;
    const int rep  = g & (NREP - 1);

#pragma unroll
    for (int r = 0; r < 12; r++) {
        const int gate = r >> 2, jl = r & 3;
        const float4* src = (const float4*)(w_hh + (size_t)(gate * HID + j0 + jl) * HID);
        w_lds[gate][jl][tid] = src[tid];
    }
    float b_r = 0.f, b_z = 0.f, b_n = 0.f;
    if (lane == 0) {
        b_r = b_hh[myj];
        b_z = b_hh[HID + myj];
        b_n = b_hh[2 * HID + myj];
    }
    __syncthreads();

    for (int i = 0; i < T_STEPS; i++) {
        const int t = T_STEPS - 1 - i;
        const unsigned int want = (unsigned int)(i & 3);
        const unsigned int* rbuf =
            pairs + ((size_t)(i & 1) * NREP + rep) * HID + tid * 4;

        // gi prefetch (issued before the poll; lane 0 only uses results --
        // compiler-managed waits; drained for free under the poll's RTT)
        float gi_r = 0.f, gi_z = 0.f, gi_n = 0.f;
        if (lane == 0) {
            const float* girow = gi + (size_t)t * N3H;
            gi_r = girow[myj];
            gi_z = girow[HID + myj];
            gi_n = girow[2 * HID + myj];
        }

        // poll: fused full-latency probes, wave-uniform exit. Re-reads of
        // already-good words are monotone-safe (header proof).
        uint4 v;
        for (;;) {
            v = load_x4_scoped(rbuf);
            if (__all(tag_ok(v, want))) break;
        }

        float4 hv;
        hv.x = __uint_as_float(v.x);
        hv.y = __uint_as_float(v.y);
        hv.z = __uint_as_float(v.z);
        hv.w = __uint_as_float(v.w);
        h_lds[i & 1][tid] = hv;
        __syncthreads();   // the ONE per-step barrier (full fence + drain)

        // wave `wave` computes the 3 recurrent dots for j = myj
        float ar = 0.f, az = 0.f, an = 0.f;
        const float4* hb = h_lds[i & 1];
        const float4* wr = w_lds[0][wave];
        const float4* wz = w_lds[1][wave];
        const float4* wn = w_lds[2][wave];
#pragma unroll
        for (int m4 = 0; m4 < 4; m4++) {
            const int idx = lane + 64 * m4;
            const float4 h4 = hb[idx];
            const float4 r4 = wr[idx];
            const float4 z4 = wz[idx];
            const float4 n4 = wn[idx];
            ar += h4.x * r4.x + h4.y * r4.y + h4.z * r4.z + h4.w * r4.w;
            az += h4.x * z4.x + h4.y * z4.y + h4.z * z4.z + h4.w * z4.w;
            an += h4.x * n4.x + h4.y * n4.y + h4.z * n4.z + h4.w * n4.w;
        }
#pragma unroll
        for (int off = 32; off > 0; off >>= 1) {
            ar += __shfl_down(ar, off);
            az += __shfl_down(az, off);
            an += __shfl_down(an, off);
        }

        if (lane == 0) {
            const float hjold = ((const float*)h_lds[i & 1])[myj];
            const float r = 1.f / (1.f + __expf(-(gi_r + ar + b_r)));
            const float z = 1.f / (1.f + __expf(-(gi_z + az + b_z)));
            const float n = tanhf(gi_n + r * (an + b_n));
            const float hnew = (1.f - z) * n + z * hjold;
            if (i == T_STEPS - 1) {
                out[myj] = hnew;
            } else {
                unsigned int* sbase =
                    pairs + (size_t)((i + 1) & 1) * NREP * HID + myj;
                const unsigned int pk =
                    (__float_as_uint(hnew) & ~3u) | (unsigned int)((i + 1) & 3);
#pragma unroll
                for (int rr = 0; rr < NREP; rr++)
                    store_scoped(sbase + rr * HID, pk);
            }
        }
        // no second barrier: next head touches h_lds[(i+1)&1] only, and the
        // global protocol blocks head i+2 (next write of h_lds[i&1]) until
        // every wave finished step i.
    }
}

// ---------------------------------------------------------------------------
extern "C" void kernel_launch(void* const* d_in, const int* in_sizes, int n_in,
                              void* d_out, int out_size, void* d_ws, size_t ws_size,
                              hipStream_t stream) {
    const float* feat = (const float*)d_in[0];  // [8192,2048]
    const float* rew  = (const float*)d_in[1];  // [8192]
    const float* w_ih = (const float*)d_in[2];  // [3072,2049]
    const float* w_hh = (const float*)d_in[3];  // [3072,1024]
    const float* b_ih = (const float*)d_in[4];  // [3072]
    const float* b_hh = (const float*)d_in[5];  // [3072]
    float* out = (float*)d_out;                 // [1024]

    float* gi = (float*)d_ws;                                   // 96 MB
    unsigned int* pairs =
        (unsigned int*)((char*)d_ws + (size_t)T_STEPS * N3H * sizeof(float));  // 64 KB

    hipLaunchKernelGGL(init_pairs, dim3((2 * NREP * HID + 255) / 256), dim3(256), 0, stream, pairs);
    hipLaunchKernelGGL(gi_gemm, dim3(N3H / GBN, T_STEPS / GBM), dim3(256), 0, stream,
                       feat, rew, w_ih, b_ih, gi);
    hipLaunchKernelGGL(gru_scan, dim3(256), dim3(256), 0, stream,
                       gi, w_hh, b_hh, pairs, out);
}